// Round 5
// baseline (168.321 us; speedup 1.0000x reference)
//
#include <hip/hip_runtime.h>
#include <hip/hip_bf16.h>

// kernel[i,j] = | prod_k cos((x[i,k]-y[j,k])/2) |
//             = | prod_k ( cos(x/2)cos(y/2) + sin(x/2)sin(y/2) ) |
//
// Dtypes (established r0-r3): inputs float32, output float32.
// Comparison is on the bf16 grid (absmax 2^-9 = 1 ulp), threshold 1.56e-2.
//
// r5 theory: qkern-attributable time ~20us vs ~4-5us structural floor
// (LDS 3.84us, VALU-pk 1.28us, HBM write 2.7us). r4 ran 2 blocks/CU =
// 2 waves/SIMD (25% occupancy) -> latency-bound, not throughput-bound
// (VALU halving in r4 moved dur -2.6us, more than a pure LDS-bound kernel
// would allow). Fix: 64x64 tile, 4x4 outputs/thread, 1024 blocks =
// 4 blocks/CU = 4 waves/SIMD. LDS/block 17KB, VGPR ~60 -> occupancy holds.
// Row-factor LDS reads are 16-lane broadcasts (free); col reads 4-way.

constexpr int D  = 16;    // wires
constexpr int BR = 64;    // rows per block
constexpr int BC = 64;    // cols per block
constexpr int BRP = BR + 4;
constexpr int BCP = BC + 4;
constexpr int NT = 256;   // threads per block (4 waves)

__global__ __launch_bounds__(NT, 4)   // 4 waves/EU -> 16 waves/CU
void qkern(const float* __restrict__ x,
           const float* __restrict__ y,
           float* __restrict__ out,
           int n, int m) {
    __shared__ float cx[D][BRP];
    __shared__ float sx[D][BRP];
    __shared__ float cy[D][BCP];
    __shared__ float sy[D][BCP];

    const int row0 = blockIdx.x * BR;
    const int col0 = blockIdx.y * BC;
    const int tid  = threadIdx.x;

    // Stage sin/cos(x/2): 64 rows x 16 k = 1024 floats, one float4/thread.
    {
        const float4 v = *(const float4*)&x[(size_t)row0 * D + tid * 4];
        const int r  = tid >> 2;          // row within tile
        const int k0 = (tid & 3) * 4;     // 4 consecutive wires
        float s, c;
        __sincosf(0.5f * v.x, &s, &c); cx[k0 + 0][r] = c; sx[k0 + 0][r] = s;
        __sincosf(0.5f * v.y, &s, &c); cx[k0 + 1][r] = c; sx[k0 + 1][r] = s;
        __sincosf(0.5f * v.z, &s, &c); cx[k0 + 2][r] = c; sx[k0 + 2][r] = s;
        __sincosf(0.5f * v.w, &s, &c); cx[k0 + 3][r] = c; sx[k0 + 3][r] = s;
    }
    // Stage sin/cos(y/2): 64 cols x 16 k, one float4/thread.
    {
        const float4 v = *(const float4*)&y[(size_t)col0 * D + tid * 4];
        const int r  = tid >> 2;
        const int k0 = (tid & 3) * 4;
        float s, c;
        __sincosf(0.5f * v.x, &s, &c); cy[k0 + 0][r] = c; sy[k0 + 0][r] = s;
        __sincosf(0.5f * v.y, &s, &c); cy[k0 + 1][r] = c; sy[k0 + 1][r] = s;
        __sincosf(0.5f * v.z, &s, &c); cy[k0 + 2][r] = c; sy[k0 + 2][r] = s;
        __sincosf(0.5f * v.w, &s, &c); cy[k0 + 3][r] = c; sy[k0 + 3][r] = s;
    }
    __syncthreads();

    const int r0 = (tid >> 4) * 4;   // row quad
    const int c0 = (tid & 15) * 4;   // col quad

    // p0[a] = cols {0,1}, p1[a] = cols {2,3} for row r0+a.
    float2 p0[4], p1[4];
#pragma unroll
    for (int a = 0; a < 4; ++a) {
        p0[a] = make_float2(1.0f, 1.0f);
        p1[a] = make_float2(1.0f, 1.0f);
    }

#pragma unroll
    for (int k = 0; k < D; ++k) {
        // 4 ds_read_b128 per k; row reads are 16-lane broadcasts.
        const float4 cxa = *(const float4*)&cx[k][r0];
        const float4 sxa = *(const float4*)&sx[k][r0];
        const float4 cyv = *(const float4*)&cy[k][c0];
        const float4 syv = *(const float4*)&sy[k][c0];

        const float2 cy01 = make_float2(cyv.x, cyv.y);
        const float2 cy23 = make_float2(cyv.z, cyv.w);
        const float2 sy01 = make_float2(syv.x, syv.y);
        const float2 sy23 = make_float2(syv.z, syv.w);

#define QROW(idx, CR, SR)                                                   \
        {                                                                   \
            float2 t0, t1;                                                  \
            t0.x = (CR) * cy01.x + (SR) * sy01.x;                           \
            t0.y = (CR) * cy01.y + (SR) * sy01.y;                           \
            t1.x = (CR) * cy23.x + (SR) * sy23.x;                           \
            t1.y = (CR) * cy23.y + (SR) * sy23.y;                           \
            p0[idx].x *= t0.x; p0[idx].y *= t0.y;                           \
            p1[idx].x *= t1.x; p1[idx].y *= t1.y;                           \
        }
        QROW(0, cxa.x, sxa.x)
        QROW(1, cxa.y, sxa.y)
        QROW(2, cxa.z, sxa.z)
        QROW(3, cxa.w, sxa.w)
#undef QROW
    }

    // Store 4 rows x 4 cols as float4 (16B-aligned).
    float* outp = out + (size_t)(row0 + r0) * m + col0 + c0;
#pragma unroll
    for (int a = 0; a < 4; ++a) {
        float4 v;
        v.x = fabsf(p0[a].x);
        v.y = fabsf(p0[a].y);
        v.z = fabsf(p1[a].x);
        v.w = fabsf(p1[a].y);
        *(float4*)(outp + (size_t)a * m) = v;
    }
}

extern "C" void kernel_launch(void* const* d_in, const int* in_sizes, int n_in,
                              void* d_out, int out_size, void* d_ws, size_t ws_size,
                              hipStream_t stream) {
    const float* x = (const float*)d_in[0];
    const float* y = (const float*)d_in[1];
    float* out = (float*)d_out;
    const int n = in_sizes[0] / D;  // 2048
    const int m = in_sizes[1] / D;  // 2048
    dim3 grid(n / BR, m / BC);      // 32 x 32 = 1024 blocks -> 4 blocks/CU
    qkern<<<grid, NT, 0, stream>>>(x, y, out, n, m);
}

// Round 7
// 65.253 us; speedup vs baseline: 2.5795x; 2.5795x over previous
//
#include <hip/hip_runtime.h>
#include <hip/hip_bf16.h>

// kernel[i,j] = | prod_k cos((x[i,k]-y[j,k])/2) |
//             = | prod_k ( cos(x/2)cos(y/2) + sin(x/2)sin(y/2) ) |
//
// Dtypes (established r0-r3): inputs float32, output float32.
//
// History: r4 (this structure, plain stores) = 66.3 us total. r5 (64x64
// tiles, 4 blocks/CU) = 168 us, qkern dispatch 118 us with WRITE_SIZE
// 224 MiB vs 16 MiB logical output -> store path is the bottleneck, via
// L2 write-allocate + dirty-poison eviction (harness streams a 256 MiB
// 0xAA fill through L2 right before qkern; every store misses and must
// evict a dirty line first).
//
// r7 = r4 byte-identical EXCEPT output stores are nontemporal
// (global_store_dwordx4 nt): bypass L2 write-allocate, no RFO, no
// poison-eviction stalls. (r6 failed to compile: the builtin needs a
// clang ext_vector_type, not HIP's float4 class.)

constexpr int D  = 16;    // wires
constexpr int BR = 128;   // rows per block
constexpr int BC = 64;    // cols per block
constexpr int BRP = BR + 4;
constexpr int BCP = BC + 4;
constexpr int NT = 256;   // threads per block (4 waves)

typedef float vf4 __attribute__((ext_vector_type(4)));

__global__ __launch_bounds__(NT)
void qkern(const float* __restrict__ x,
           const float* __restrict__ y,
           float* __restrict__ out,
           int n, int m) {
    __shared__ float cx[D][BRP];
    __shared__ float sx[D][BRP];
    __shared__ float cy[D][BCP];
    __shared__ float sy[D][BCP];

    const int row0 = blockIdx.x * BR;
    const int col0 = blockIdx.y * BC;
    const int tid  = threadIdx.x;

    // Stage sin/cos(x/2) for 128 rows (2048 vals, 8/thread).
    for (int i = tid; i < BR * D; i += NT) {
        float v = x[(size_t)row0 * D + i];
        int r = i >> 4, k = i & 15;
        float s, c;
        __sincosf(0.5f * v, &s, &c);
        cx[k][r] = c;
        sx[k][r] = s;
    }
    // Stage sin/cos(y/2) for 64 cols (1024 vals, 4/thread).
    for (int i = tid; i < BC * D; i += NT) {
        float v = y[(size_t)col0 * D + i];
        int r = i >> 4, k = i & 15;
        float s, c;
        __sincosf(0.5f * v, &s, &c);
        cy[k][r] = c;
        sy[k][r] = s;
    }
    __syncthreads();

    const int rg = tid >> 4;   // row quads at rg*4 and rg*4+64
    const int cg = tid & 15;   // col quad at cg*4
    const int r0 = rg * 4;
    const int c0 = cg * 4;

    // p0[a] = cols {0,1}, p1[a] = cols {2,3} for row a (a<4: r0+a, a>=4: r0+64+a-4)
    float2 p0[8], p1[8];
#pragma unroll
    for (int a = 0; a < 8; ++a) {
        p0[a] = make_float2(1.0f, 1.0f);
        p1[a] = make_float2(1.0f, 1.0f);
    }

#pragma unroll
    for (int k = 0; k < D; ++k) {
        // 6 ds_read_b128 per k (16B-aligned: BRP/BCP multiples of 4).
        const float4 cxa = *(const float4*)&cx[k][r0];
        const float4 sxa = *(const float4*)&sx[k][r0];
        const float4 cxb = *(const float4*)&cx[k][r0 + 64];
        const float4 sxb = *(const float4*)&sx[k][r0 + 64];
        const float4 cyv = *(const float4*)&cy[k][c0];
        const float4 syv = *(const float4*)&sy[k][c0];

        const float2 cy01 = make_float2(cyv.x, cyv.y);
        const float2 cy23 = make_float2(cyv.z, cyv.w);
        const float2 sy01 = make_float2(syv.x, syv.y);
        const float2 sy23 = make_float2(syv.z, syv.w);

        // t = c_x*c_y + s_x*s_y, p *= t  -- as <2 x float> packed ops.
#define QROW(idx, CR, SR)                                                   \
        {                                                                   \
            const float2 cax = make_float2((CR), (CR));                     \
            const float2 sax = make_float2((SR), (SR));                     \
            float2 t0, t1;                                                  \
            t0.x = cax.x * cy01.x + sax.x * sy01.x;                         \
            t0.y = cax.y * cy01.y + sax.y * sy01.y;                         \
            t1.x = cax.x * cy23.x + sax.x * sy23.x;                         \
            t1.y = cax.y * cy23.y + sax.y * sy23.y;                         \
            p0[idx].x *= t0.x; p0[idx].y *= t0.y;                           \
            p1[idx].x *= t1.x; p1[idx].y *= t1.y;                           \
        }

        QROW(0, cxa.x, sxa.x)
        QROW(1, cxa.y, sxa.y)
        QROW(2, cxa.z, sxa.z)
        QROW(3, cxa.w, sxa.w)
        QROW(4, cxb.x, sxb.x)
        QROW(5, cxb.y, sxb.y)
        QROW(6, cxb.z, sxb.z)
        QROW(7, cxb.w, sxb.w)
#undef QROW
    }

    // Store 8 rows x 4 cols as NONTEMPORAL 16B stores (bypass L2
    // write-allocate so stores don't evict the harness's dirty poison lines).
    float* outp = out + (size_t)(row0 + r0) * m + col0 + c0;
    const size_t hstep = (size_t)64 * m;
#pragma unroll
    for (int a = 0; a < 8; ++a) {
        vf4 v;
        v.x = fabsf(p0[a].x);
        v.y = fabsf(p0[a].y);
        v.z = fabsf(p1[a].x);
        v.w = fabsf(p1[a].y);
        float* dst = outp + (size_t)(a & 3) * m + ((a >> 2) ? hstep : 0);
        __builtin_nontemporal_store(v, (vf4*)dst);
    }
}

extern "C" void kernel_launch(void* const* d_in, const int* in_sizes, int n_in,
                              void* d_out, int out_size, void* d_ws, size_t ws_size,
                              hipStream_t stream) {
    const float* x = (const float*)d_in[0];
    const float* y = (const float*)d_in[1];
    float* out = (float*)d_out;
    const int n = in_sizes[0] / D;  // 2048
    const int m = in_sizes[1] / D;  // 2048
    dim3 grid(n / BR, m / BC);      // 16 x 32 = 512 blocks -> 2 blocks/CU
    qkern<<<grid, NT, 0, stream>>>(x, y, out, n, m);
}

// Round 8
// 64.258 us; speedup vs baseline: 2.6195x; 1.0155x over previous
//
#include <hip/hip_runtime.h>
#include <hip/hip_bf16.h>

// kernel[i,j] = | prod_k cos((x[i,k]-y[j,k])/2) |
//             = | prod_k ( cos(x/2)cos(y/2) + sin(x/2)sin(y/2) ) |
//
// Dtypes (established r0-r3): inputs float32, output float32.
//
// History:
//   r4: 128x64 tile, 2 blk/CU, plain stores           -> 66.3 us
//   r5: 64x64 tile, 4 blk/CU, launch_bounds(256,4)    -> 168 us
//       POST-MORTEM (r7): VGPR_Count=64 == the (256,4) cap -> forced
//       scratch spills; WRITE_SIZE 224 MiB = ~900 B/thread spill traffic.
//       r5 tested spilling, not occupancy.
//   r7: r4 + nontemporal stores                       -> 65.25 us
//
// r8 = r5's occupancy experiment WITHOUT the VGPR cap: 64x64 tile,
// 4x4 outputs/thread, 1024 blocks = 4 blk/CU = 4 waves/SIMD (2x r7),
// __launch_bounds__(256) only, NT stores. Tests the latency-bound theory
// cleanly (r3->r4 VALU halving gave -2.6us => not pure LDS-BW-bound).

constexpr int D  = 16;    // wires
constexpr int BR = 64;    // rows per block
constexpr int BC = 64;    // cols per block
constexpr int BRP = BR + 4;
constexpr int BCP = BC + 4;
constexpr int NT = 256;   // threads per block (4 waves)

typedef float vf4 __attribute__((ext_vector_type(4)));

__global__ __launch_bounds__(NT)   // NO min-waves arg: do not cap VGPRs
void qkern(const float* __restrict__ x,
           const float* __restrict__ y,
           float* __restrict__ out,
           int n, int m) {
    __shared__ float cx[D][BRP];
    __shared__ float sx[D][BRP];
    __shared__ float cy[D][BCP];
    __shared__ float sy[D][BCP];

    const int row0 = blockIdx.x * BR;
    const int col0 = blockIdx.y * BC;
    const int tid  = threadIdx.x;

    // Stage sin/cos(x/2): 64 rows x 16 k = 1024 floats, one float4/thread.
    {
        const float4 v = *(const float4*)&x[(size_t)row0 * D + tid * 4];
        const int r  = tid >> 2;          // row within tile
        const int k0 = (tid & 3) * 4;     // 4 consecutive wires
        float s, c;
        __sincosf(0.5f * v.x, &s, &c); cx[k0 + 0][r] = c; sx[k0 + 0][r] = s;
        __sincosf(0.5f * v.y, &s, &c); cx[k0 + 1][r] = c; sx[k0 + 1][r] = s;
        __sincosf(0.5f * v.z, &s, &c); cx[k0 + 2][r] = c; sx[k0 + 2][r] = s;
        __sincosf(0.5f * v.w, &s, &c); cx[k0 + 3][r] = c; sx[k0 + 3][r] = s;
    }
    // Stage sin/cos(y/2): 64 cols x 16 k, one float4/thread.
    {
        const float4 v = *(const float4*)&y[(size_t)col0 * D + tid * 4];
        const int r  = tid >> 2;
        const int k0 = (tid & 3) * 4;
        float s, c;
        __sincosf(0.5f * v.x, &s, &c); cy[k0 + 0][r] = c; sy[k0 + 0][r] = s;
        __sincosf(0.5f * v.y, &s, &c); cy[k0 + 1][r] = c; sy[k0 + 1][r] = s;
        __sincosf(0.5f * v.z, &s, &c); cy[k0 + 2][r] = c; sy[k0 + 2][r] = s;
        __sincosf(0.5f * v.w, &s, &c); cy[k0 + 3][r] = c; sy[k0 + 3][r] = s;
    }
    __syncthreads();

    const int r0 = (tid >> 4) * 4;   // row quad
    const int c0 = (tid & 15) * 4;   // col quad

    // p0[a] = cols {0,1}, p1[a] = cols {2,3} for row r0+a.
    float2 p0[4], p1[4];
#pragma unroll
    for (int a = 0; a < 4; ++a) {
        p0[a] = make_float2(1.0f, 1.0f);
        p1[a] = make_float2(1.0f, 1.0f);
    }

#pragma unroll
    for (int k = 0; k < D; ++k) {
        // 4 ds_read_b128 per k; row reads broadcast across 16-lane groups.
        const float4 cxa = *(const float4*)&cx[k][r0];
        const float4 sxa = *(const float4*)&sx[k][r0];
        const float4 cyv = *(const float4*)&cy[k][c0];
        const float4 syv = *(const float4*)&sy[k][c0];

        const float2 cy01 = make_float2(cyv.x, cyv.y);
        const float2 cy23 = make_float2(cyv.z, cyv.w);
        const float2 sy01 = make_float2(syv.x, syv.y);
        const float2 sy23 = make_float2(syv.z, syv.w);

#define QROW(idx, CR, SR)                                                   \
        {                                                                   \
            float2 t0, t1;                                                  \
            t0.x = (CR) * cy01.x + (SR) * sy01.x;                           \
            t0.y = (CR) * cy01.y + (SR) * sy01.y;                           \
            t1.x = (CR) * cy23.x + (SR) * sy23.x;                           \
            t1.y = (CR) * cy23.y + (SR) * sy23.y;                           \
            p0[idx].x *= t0.x; p0[idx].y *= t0.y;                           \
            p1[idx].x *= t1.x; p1[idx].y *= t1.y;                           \
        }
        QROW(0, cxa.x, sxa.x)
        QROW(1, cxa.y, sxa.y)
        QROW(2, cxa.z, sxa.z)
        QROW(3, cxa.w, sxa.w)
#undef QROW
    }

    // Store 4 rows x 4 cols as nontemporal 16B stores.
    float* outp = out + (size_t)(row0 + r0) * m + col0 + c0;
#pragma unroll
    for (int a = 0; a < 4; ++a) {
        vf4 v;
        v.x = fabsf(p0[a].x);
        v.y = fabsf(p0[a].y);
        v.z = fabsf(p1[a].x);
        v.w = fabsf(p1[a].y);
        __builtin_nontemporal_store(v, (vf4*)(outp + (size_t)a * m));
    }
}

extern "C" void kernel_launch(void* const* d_in, const int* in_sizes, int n_in,
                              void* d_out, int out_size, void* d_ws, size_t ws_size,
                              hipStream_t stream) {
    const float* x = (const float*)d_in[0];
    const float* y = (const float*)d_in[1];
    float* out = (float*)d_out;
    const int n = in_sizes[0] / D;  // 2048
    const int m = in_sizes[1] / D;  // 2048
    dim3 grid(n / BR, m / BC);      // 32 x 32 = 1024 blocks -> 4 blocks/CU
    qkern<<<grid, NT, 0, stream>>>(x, y, out, n, m);
}